// Round 11
// baseline (359.202 us; speedup 1.0000x reference)
//
#include <hip/hip_runtime.h>
#include <cstddef>
#include <cstdint>

#define NPTS 8192
#define DIM  128

// MFMA path: 128x128 tiles, K3=256 split-bf16 (A'=[hi|lo] . B'=[hi|hi]).
// BK=32 per staged step (8 KB A + 8 KB B per buffer, 32 KB double-buffered)
// -> 3 blocks/CU at launch_bounds(256,3); NSPLIT=16 -> grid 1024 so the
// extra residency is actually used. 1 barrier per step, packed-key top-6,
// zero-fill interleaved (2 nt f32x4/thread/step).
#define K3      256
#define BK      32
#define KCH     (K3 / BK)        // 8 k-steps per tile
#define BM      128
#define BN      128
#define NSPLIT  16
#define CPB2    (NPTS / NSPLIT)  // 512
#define NT2     (CPB2 / BN)      // 4

using bf16x8 = __attribute__((ext_vector_type(8))) short;
using f32x4  = __attribute__((ext_vector_type(4))) float;

// ws layout (bytes): Hi | Lo | sq | part (8192 rows x 16 splits x 6 packed keys)
#define WS_HI   ((size_t)0)
#define WS_LO   ((size_t)NPTS * DIM * 2)            // 2 MB
#define WS_SQ   ((size_t)2 * NPTS * DIM * 2)        // 4 MB
#define WS_PART (WS_SQ + (size_t)NPTS * 4)          // +32 KB
#define WS_NEED (WS_PART + (size_t)NPTS * 96 * 4)   // ~8.8 MB

// branchless sorted-ascending insert of packed key (positive floats only)
__device__ __forceinline__ void ins6(float t, float bd[6]) {
#pragma unroll
    for (int q = 0; q < 6; ++q) {
        float lo = fminf(bd[q], t);
        t        = fmaxf(bd[q], t);
        bd[q]    = lo;
    }
}

// classic (d2, idx) insert for the small final merge
__device__ __forceinline__ void insert6(float d, int idx, float bd[6], int bi[6]) {
    if (d < bd[5]) {
        bd[5] = d; bi[5] = idx;
#pragma unroll
        for (int q = 5; q >= 1; --q) {
            if (bd[q] < bd[q - 1]) {
                float td = bd[q]; bd[q] = bd[q - 1]; bd[q - 1] = td;
                int   ti = bi[q]; bi[q] = bi[q - 1]; bi[q - 1] = ti;
            }
        }
    }
}

__device__ __forceinline__ void async16(const void* g, void* l) {
    __builtin_amdgcn_global_load_lds(
        (const __attribute__((address_space(1))) void*)g,
        (__attribute__((address_space(3))) void*)l,
        16, 0, 0);
}

// K0: elementwise fp32 -> (hi, lo) bf16 planes + per-row |f|^2 via shfl reduce.
__global__ __launch_bounds__(256) void prep2(const float* __restrict__ F,
                                             short* __restrict__ Hi,
                                             short* __restrict__ Lo,
                                             float* __restrict__ sq) {
    __shared__ float wsum[4];
    const int tid = threadIdx.x;
    const int idx = blockIdx.x * 256 + tid;
    float f = F[idx];
    uint32_t u  = __float_as_uint(f);
    uint32_t hb = (u + 0x7fffu + ((u >> 16) & 1u)) >> 16;     // RNE to bf16
    float hf = __uint_as_float(hb << 16);
    float lo = f - hf;
    uint32_t ul = __float_as_uint(lo);
    uint32_t lb = (ul + 0x7fffu + ((ul >> 16) & 1u)) >> 16;
    float lf = __uint_as_float(lb << 16);
    Hi[idx] = (short)hb;
    Lo[idx] = (short)lb;
    float fh = hf + lf;          // the value the GEMM's A-side sees
    float s  = fh * fh;
#pragma unroll
    for (int m = 32; m >= 1; m >>= 1) s += __shfl_xor(s, m, 64);
    if ((tid & 63) == 0) wsum[tid >> 6] = s;
    __syncthreads();
    if (tid < 2) sq[blockIdx.x * 2 + tid] = wsum[tid * 2] + wsum[tid * 2 + 1];
}

// K1: swapped-operand MFMA distance + packed-key top-6 + interleaved zero-fill.
// BK=32: LDS buffer = 8KB A + 8KB B; chunk swizzle uses point bits [2:1]
// (p*64B only alternates two bank groups, so a p&3 swizzle would 4-way
// conflict; (p>>1)&3 gives 2-way = free).
__global__ __launch_bounds__(256, 3) void knn_mfma4(const short* __restrict__ Hi,
                                                    const short* __restrict__ Lo,
                                                    const float* __restrict__ sq,
                                                    float* __restrict__ part,
                                                    float* __restrict__ out) {
    __shared__ __align__(16) char smraw[32768];   // 2 x (8KB A | 8KB B); dump reuses 24KB

    const int tid  = threadIdx.x;
    const int lane = tid & 63;
    const int w    = tid >> 6;        // wave 0..3
    const int wy   = w >> 1;          // col half
    const int wx   = w & 1;           // row half
    const int q    = lane >> 4;       // quad 0..3
    const int pl   = lane & 15;

    const int bx   = blockIdx.x;
    const int rb   = bx & 63;         // 64 row blocks
    const int cs   = bx >> 6;         // 16 col splits
    const int row0 = rb * BM;
    const int col0 = cs * CPB2;

    // staging decode: slot = w*128 + i*64 + lane (i<2) -> (point, logical chunk)
    // phys slot s holds logical chunk (s&3) ^ ((p>>1)&3), p = s>>2.
    int pS[2], cS[2];
#pragma unroll
    for (int i = 0; i < 2; ++i) {
        int slot = w * 128 + i * 64 + lane;
        pS[i] = slot >> 2;
        cS[i] = (slot & 3) ^ ((pS[i] >> 1) & 3);
    }

    // frag LDS byte offsets: phys chunk = p*4 + (q ^ ((p>>1)&3))
    int colOff[4], rowOff[4];
#pragma unroll
    for (int f = 0; f < 4; ++f) {
        int pc = wy * 64 + f * 16 + pl;
        colOff[f] = (pc * 4 + (q ^ ((pc >> 1) & 3))) * 16;
        int pr = wx * 64 + f * 16 + pl;
        rowOff[f] = (pr * 4 + (q ^ ((pr >> 1) & 3))) * 16;
    }

    float sqr4[4];
#pragma unroll
    for (int fj = 0; fj < 4; ++fj) sqr4[fj] = sq[row0 + wx * 64 + fj * 16 + pl];

    // packed-key top-6 per owned row (4 rows per thread)
    float bd[4][6];
#pragma unroll
    for (int fj = 0; fj < 4; ++fj)
#pragma unroll
        for (int k = 0; k < 6; ++k) bd[fj][k] = 3.0e38f;

    auto stage = [&](int b, int nt, int nk) {
        const short* plA = (nk >= 4) ? Lo : Hi;     // A sections: hi(0..3), lo(4..7)
        const short* plB = Hi;                      // B sections: hi, hi
        const int half = (nk & 3) * 32;
        const int tcn  = col0 + nt * BN;
        char* baseA = smraw + b * 16384;
        char* baseB = baseA + 8192;
#pragma unroll
        for (int i = 0; i < 2; ++i) {
            int slot = w * 128 + i * 64 + lane;
            const short* gA = plA + (size_t)(row0 + pS[i]) * DIM + half + cS[i] * 8;
            async16(gA, baseA + slot * 16);
            const short* gB = plB + (size_t)(tcn + pS[i]) * DIM + half + cS[i] * 8;
            async16(gB, baseB + slot * 16);
        }
    };

    stage(0, 0, 0);
    int sidx = 0;

    const f32x4 z4 = {0.f, 0.f, 0.f, 0.f};

    for (int tile = 0; tile < NT2; ++tile) {
        const int tc0 = col0 + tile * BN;

        f32x4 acc[4][4];
#pragma unroll
        for (int fi = 0; fi < 4; ++fi)
#pragma unroll
            for (int fj = 0; fj < 4; ++fj) acc[fi][fj] = 0.0f;

        for (int kk = 0; kk < KCH; ++kk) {
            const int b = sidx & 1;
            __syncthreads();
            int nk = kk + 1, nt = tile;
            if (nk == KCH) { nk = 0; nt = tile + 1; }
            if (nt < NT2) stage(b ^ 1, nt, nk);

            // interleaved zero-fill: 2 f32x4/thread/step.
            // 32 steps x 512 f32x4 = 16384 = full 128x512 region.
            {
                int base = sidx * 512 + tid;
#pragma unroll
                for (int it = 0; it < 2; ++it) {
                    int flat = base + it * 256;
                    int r  = flat >> 7;           // 0..127  (128 f32x4 per row)
                    int c4 = (flat & 127) * 4;    // 0..508
                    __builtin_nontemporal_store(
                        z4, (f32x4*)&out[(size_t)(row0 + r) * NPTS + col0 + c4]);
                }
            }

            char* baseA = smraw + b * 16384;
            char* baseB = baseA + 8192;
            bf16x8 cf[4], rf[4];
#pragma unroll
            for (int fi = 0; fi < 4; ++fi)
                cf[fi] = *(const bf16x8*)(baseB + colOff[fi]);
#pragma unroll
            for (int fj = 0; fj < 4; ++fj)
                rf[fj] = *(const bf16x8*)(baseA + rowOff[fj]);
#pragma unroll
            for (int fi = 0; fi < 4; ++fi)
#pragma unroll
                for (int fj = 0; fj < 4; ++fj)
                    acc[fi][fj] = __builtin_amdgcn_mfma_f32_16x16x32_bf16(
                        cf[fi], rf[fj], acc[fi][fj], 0, 0, 0);
            ++sidx;
        }

        // in-register epilogue: rows r = wx*64+fj*16+pl, cols c = wy*64+fi*16+q*4+reg
        const bool diag = (tc0 == row0);
        float4 sqc4[4];
#pragma unroll
        for (int fi = 0; fi < 4; ++fi)
            sqc4[fi] = *(const float4*)&sq[tc0 + wy * 64 + fi * 16 + q * 4];

#pragma unroll
        for (int fj = 0; fj < 4; ++fj) {
            const float sr = sqr4[fj];
            const int   r  = wx * 64 + fj * 16 + pl;
#pragma unroll
            for (int fi = 0; fi < 4; ++fi) {
                const float* sc = (const float*)&sqc4[fi];
#pragma unroll
                for (int reg = 0; reg < 4; ++reg) {
                    const int c = wy * 64 + fi * 16 + q * 4 + reg;
                    float d2 = fmaf(-2.0f, acc[fi][fj][reg], sr + sc[reg]);
                    d2 = fmaxf(d2, 1e-30f);
                    if (diag && r == c) d2 = 1e-30f;    // self-distance
                    uint32_t kb = (__float_as_uint(d2) & 0xFFFFFC00u)
                                  | (uint32_t)(tile * BN + c);   // local col < 512
                    ins6(__uint_as_float(kb), bd[fj]);
                }
            }
        }
    }

    // block merge: 8 lists per row (wy x q) -> 6 packed keys per row per split
    __syncthreads();                       // all frag reads done; reuse smraw
    float* dump = (float*)smraw;           // 128 rows * 8 copies * 6 = 24 KB <= 32 KB
#pragma unroll
    for (int fj = 0; fj < 4; ++fj) {
        const int r    = wx * 64 + fj * 16 + pl;
        const int copy = wy * 4 + q;
        float* d = &dump[(size_t)(r * 8 + copy) * 6];
#pragma unroll
        for (int k = 0; k < 6; ++k) d[k] = bd[fj][k];
    }
    __syncthreads();
    if (tid < 128) {
        float md[6];
#pragma unroll
        for (int k = 0; k < 6; ++k) md[k] = 3.0e38f;
        const float* src = &dump[(size_t)tid * 48];
#pragma unroll
        for (int g = 0; g < 48; ++g) ins6(src[g], md);
        float* dst = part + (size_t)(row0 + tid) * 96 + cs * 6;
#pragma unroll
        for (int k = 0; k < 6; ++k) dst[k] = md[k];
    }
}

// K2: merge 16 packed-key lists per row (direct global reads, no LDS),
// compute weights, scatter 6 values.
__global__ __launch_bounds__(256) void final3(const float* __restrict__ part,
                                              float* __restrict__ out) {
    const int r = blockIdx.x * 256 + threadIdx.x;
    const float4* p4 = (const float4*)(part + (size_t)r * 96);
    float4 buf[24];
#pragma unroll
    for (int i = 0; i < 24; ++i) buf[i] = p4[i];
    const float* keys = (const float*)buf;

    float md[6]; int mi[6];
#pragma unroll
    for (int k = 0; k < 6; ++k) { md[k] = 3.0e38f; mi[k] = 0; }
#pragma unroll
    for (int s = 0; s < 16; ++s)
#pragma unroll
        for (int k = 0; k < 6; ++k) {
            uint32_t kb = __float_as_uint(keys[s * 6 + k]);
            float d2 = __uint_as_float(kb & 0xFFFFFC00u);
            int  col = s * CPB2 + (int)(kb & 1023u);
            insert6(d2, col, md, mi);
        }
    const float T = sqrtf(md[5]);
    float wv[6], norm = 0.f;
#pragma unroll
    for (int k = 0; k < 6; ++k) { wv[k] = T - sqrtf(md[k]) + 1e-10f; norm += wv[k]; }
    const float inv = 1.0f / fmaxf(norm, 1e-12f);
    const size_t base = (size_t)r * NPTS;
#pragma unroll
    for (int k = 0; k < 6; ++k) out[base + mi[k]] = wv[k] * inv;
}

// ------------------- fallback fp32 path (round 1, passing) -------------------
#define RB      32
#define CT      64
#define SPLITS  8
#define CPB     (NPTS / SPLITS)
#define NTILES  (CPB / CT)
#define PADS    132

__global__ __launch_bounds__(256) void knn_partial(const float* __restrict__ F,
                                                   float* __restrict__ out) {
    __shared__ float rowF[RB * PADS];
    __shared__ float colF[CT * PADS];
    __shared__ float sqr[RB];
    __shared__ float sqc[CT];

    const int tid  = threadIdx.x;
    const int bx   = blockIdx.x;
    const int rb   = bx & ((NPTS / RB) - 1);
    const int cs   = bx >> 8;
    const int row0 = rb * RB;
    const int col0 = cs * CPB;

#pragma unroll
    for (int m = 0; m < 4; ++m) {
        int flat = m * 256 + tid;
        int r = flat >> 5, kq = flat & 31;
        float4 v = *(const float4*)&F[(size_t)(row0 + r) * DIM + kq * 4];
        *(float4*)&rowF[r * PADS + kq * 4] = v;
    }
    __syncthreads();
    if (tid < RB) {
        float s = 0.f;
#pragma unroll
        for (int kq = 0; kq < 32; ++kq) {
            float4 v = *(const float4*)&rowF[tid * PADS + kq * 4];
            s += v.x * v.x + v.y * v.y + v.z * v.z + v.w * v.w;
        }
        sqr[tid] = s;
    }

    const int rl = tid >> 4;
    const int cl = tid & 15;

    float bd[2][6];
    int   bi[2][6];
#pragma unroll
    for (int i = 0; i < 2; ++i)
#pragma unroll
        for (int k = 0; k < 6; ++k) { bd[i][k] = 3.0e38f; bi[i][k] = 0; }

    for (int t = 0; t < NTILES; ++t) {
        const int cbase = col0 + t * CT;
        __syncthreads();
#pragma unroll
        for (int m = 0; m < 8; ++m) {
            int flat = m * 256 + tid;
            int c = flat >> 5, kq = flat & 31;
            float4 v = *(const float4*)&F[(size_t)(cbase + c) * DIM + kq * 4];
            *(float4*)&colF[c * PADS + kq * 4] = v;
        }
        __syncthreads();
        if (tid < CT) {
            float s = 0.f;
#pragma unroll
            for (int kq = 0; kq < 32; ++kq) {
                float4 v = *(const float4*)&colF[tid * PADS + kq * 4];
                s += v.x * v.x + v.y * v.y + v.z * v.z + v.w * v.w;
            }
            sqc[tid] = s;
        }
        __syncthreads();

        float acc[2][4];
#pragma unroll
        for (int i = 0; i < 2; ++i)
#pragma unroll
            for (int j = 0; j < 4; ++j) acc[i][j] = 0.f;

#pragma unroll 4
        for (int kq = 0; kq < 32; ++kq) {
            float4 a[2], b[4];
#pragma unroll
            for (int i = 0; i < 2; ++i)
                a[i] = *(const float4*)&rowF[(rl + 16 * i) * PADS + kq * 4];
#pragma unroll
            for (int j = 0; j < 4; ++j)
                b[j] = *(const float4*)&colF[(cl + 16 * j) * PADS + kq * 4];
#pragma unroll
            for (int i = 0; i < 2; ++i)
#pragma unroll
                for (int j = 0; j < 4; ++j) {
                    acc[i][j] = fmaf(a[i].x, b[j].x, acc[i][j]);
                    acc[i][j] = fmaf(a[i].y, b[j].y, acc[i][j]);
                    acc[i][j] = fmaf(a[i].z, b[j].z, acc[i][j]);
                    acc[i][j] = fmaf(a[i].w, b[j].w, acc[i][j]);
                }
        }

#pragma unroll
        for (int i = 0; i < 2; ++i) {
            const int r = rl + 16 * i;
            const int gr = row0 + r;
#pragma unroll
            for (int j = 0; j < 4; ++j) {
                const int c = cl + 16 * j;
                const int gc = cbase + c;
                float d2 = sqr[r] + sqc[c] - 2.0f * acc[i][j];
                d2 = (gr == gc) ? 1e-30f : fmaxf(d2, 1e-30f);
                insert6(d2, gc, bd[i], bi[i]);
            }
        }
    }

    __syncthreads();
    float* cd = colF;
    float* ci = rowF;
#pragma unroll
    for (int i = 0; i < 2; ++i) {
        const int r = rl + 16 * i;
#pragma unroll
        for (int k = 0; k < 6; ++k) {
            cd[(r * 16 + cl) * 6 + k] = bd[i][k];
            ci[(r * 16 + cl) * 6 + k] = __int_as_float(bi[i][k]);
        }
    }
    __syncthreads();
    if (tid < RB) {
        float md[6]; int mi[6];
#pragma unroll
        for (int k = 0; k < 6; ++k) { md[k] = 3.0e38f; mi[k] = 0; }
        for (int g = 0; g < 16; ++g) {
#pragma unroll
            for (int k = 0; k < 6; ++k)
                insert6(cd[(tid * 16 + g) * 6 + k],
                        __float_as_int(ci[(tid * 16 + g) * 6 + k]), md, mi);
        }
        float* dst = &out[(size_t)(row0 + tid) * NPTS + cs * 12];
#pragma unroll
        for (int k = 0; k < 6; ++k) {
            dst[k] = md[k];
            dst[6 + k] = __int_as_float(mi[k]);
        }
    }
}

__global__ __launch_bounds__(256) void knn_finalize(float* __restrict__ out) {
    __shared__ float pbuf[SPLITS * 12];
    __shared__ float w_s[6];
    __shared__ int   wi_s[6];

    const int    tid  = threadIdx.x;
    const size_t base = (size_t)blockIdx.x * NPTS;

    if (tid < SPLITS * 12) pbuf[tid] = out[base + tid];
    __syncthreads();

    if (tid == 0) {
        float md[6]; int mi[6];
#pragma unroll
        for (int k = 0; k < 6; ++k) { md[k] = 3.0e38f; mi[k] = 0; }
        for (int s = 0; s < SPLITS; ++s)
#pragma unroll
            for (int k = 0; k < 6; ++k)
                insert6(pbuf[s * 12 + k], __float_as_int(pbuf[s * 12 + 6 + k]), md, mi);
        const float T = sqrtf(md[5]);
        float w[6]; float norm = 0.f;
#pragma unroll
        for (int k = 0; k < 6; ++k) { w[k] = T - sqrtf(md[k]) + 1e-10f; norm += w[k]; }
        const float inv = 1.0f / fmaxf(norm, 1e-12f);
#pragma unroll
        for (int k = 0; k < 6; ++k) { w_s[k] = w[k] * inv; wi_s[k] = mi[k]; }
    }
    __syncthreads();

#pragma unroll
    for (int m = 0; m < 8; ++m)
        *(float4*)&out[base + (size_t)(m * 256 + tid) * 4] = make_float4(0.f, 0.f, 0.f, 0.f);
    __syncthreads();

    if (tid < 6) out[base + wi_s[tid]] = w_s[tid];
}

extern "C" void kernel_launch(void* const* d_in, const int* in_sizes, int n_in,
                              void* d_out, int out_size, void* d_ws, size_t ws_size,
                              hipStream_t stream) {
    const float* F   = (const float*)d_in[0];
    float*       out = (float*)d_out;
    if (ws_size >= WS_NEED) {
        short* Hi  = (short*)((char*)d_ws + WS_HI);
        short* Lo  = (short*)((char*)d_ws + WS_LO);
        float* sqp = (float*)((char*)d_ws + WS_SQ);
        float* prt = (float*)((char*)d_ws + WS_PART);
        prep2<<<dim3(NPTS * DIM / 256), dim3(256), 0, stream>>>(F, Hi, Lo, sqp);
        knn_mfma4<<<dim3(64 * NSPLIT), dim3(256), 0, stream>>>(Hi, Lo, sqp, prt, out);
        final3<<<dim3(NPTS / 256), dim3(256), 0, stream>>>(prt, out);
    } else {
        knn_partial<<<dim3((NPTS / RB) * SPLITS), dim3(256), 0, stream>>>(F, out);
        knn_finalize<<<dim3(NPTS), dim3(256), 0, stream>>>(out);
    }
}

// Round 12
// 297.165 us; speedup vs baseline: 1.2088x; 1.2088x over previous
//
#include <hip/hip_runtime.h>
#include <cstddef>
#include <cstdint>

#define NPTS 8192
#define DIM  128

// MFMA path (round-10 configuration — best verified; R11's BK=32/NSPLIT=16
// occupancy experiment regressed +55us and is reverted):
// 128x128 tiles, K3=256 split-bf16 (A'=[hi|lo] . B'=[hi|hi], i.e.
// (hiA+loA).hiB — drops the hiA.loB term; error ~0.025 RMS on d^2, under the
// 2e-2 gate). BK=64 per staged step, double-buffered LDS, 1 barrier per step,
// packed-key top-6, zero-fill interleaved (4 f32x4/thread/step, regular stores).
#define K3      256
#define BK      64
#define KITERS  (K3 / BK)        // 4
#define BM      128
#define BN      128
#define NSPLIT  8
#define CPB2    (NPTS / NSPLIT)  // 1024
#define NT2     (CPB2 / BN)      // 8

using bf16x8 = __attribute__((ext_vector_type(8))) short;
using f32x4  = __attribute__((ext_vector_type(4))) float;

// ws layout (bytes): Hi | Lo | sq | part (8192 rows x 8 splits x 6 packed keys)
#define WS_HI   ((size_t)0)
#define WS_LO   ((size_t)NPTS * DIM * 2)            // 2 MB
#define WS_SQ   ((size_t)2 * NPTS * DIM * 2)        // 4 MB
#define WS_PART (WS_SQ + (size_t)NPTS * 4)          // +32 KB
#define WS_NEED (WS_PART + (size_t)NPTS * 48 * 4)   // ~5.7 MB

// branchless sorted-ascending insert of packed key (positive floats only)
__device__ __forceinline__ void ins6(float t, float bd[6]) {
#pragma unroll
    for (int q = 0; q < 6; ++q) {
        float lo = fminf(bd[q], t);
        t        = fmaxf(bd[q], t);
        bd[q]    = lo;
    }
}

// classic (d2, idx) insert for the small final merge
__device__ __forceinline__ void insert6(float d, int idx, float bd[6], int bi[6]) {
    if (d < bd[5]) {
        bd[5] = d; bi[5] = idx;
#pragma unroll
        for (int q = 5; q >= 1; --q) {
            if (bd[q] < bd[q - 1]) {
                float td = bd[q]; bd[q] = bd[q - 1]; bd[q - 1] = td;
                int   ti = bi[q]; bi[q] = bi[q - 1]; bi[q - 1] = ti;
            }
        }
    }
}

__device__ __forceinline__ void async16(const void* g, void* l) {
    __builtin_amdgcn_global_load_lds(
        (const __attribute__((address_space(1))) void*)g,
        (__attribute__((address_space(3))) void*)l,
        16, 0, 0);
}

// K0: elementwise fp32 -> (hi, lo) bf16 planes + per-row |f|^2 via shfl reduce.
__global__ __launch_bounds__(256) void prep2(const float* __restrict__ F,
                                             short* __restrict__ Hi,
                                             short* __restrict__ Lo,
                                             float* __restrict__ sq) {
    __shared__ float wsum[4];
    const int tid = threadIdx.x;
    const int idx = blockIdx.x * 256 + tid;
    float f = F[idx];
    uint32_t u  = __float_as_uint(f);
    uint32_t hb = (u + 0x7fffu + ((u >> 16) & 1u)) >> 16;     // RNE to bf16
    float hf = __uint_as_float(hb << 16);
    float lo = f - hf;
    uint32_t ul = __float_as_uint(lo);
    uint32_t lb = (ul + 0x7fffu + ((ul >> 16) & 1u)) >> 16;
    float lf = __uint_as_float(lb << 16);
    Hi[idx] = (short)hb;
    Lo[idx] = (short)lb;
    float fh = hf + lf;          // the value the GEMM's A-side sees
    float s  = fh * fh;
#pragma unroll
    for (int m = 32; m >= 1; m >>= 1) s += __shfl_xor(s, m, 64);
    if ((tid & 63) == 0) wsum[tid >> 6] = s;
    __syncthreads();
    if (tid < 2) sq[blockIdx.x * 2 + tid] = wsum[tid * 2] + wsum[tid * 2 + 1];
}

// K1: swapped-operand MFMA distance + packed-key top-6 + interleaved zero-fill.
__global__ __launch_bounds__(256, 2) void knn_mfma3(const short* __restrict__ Hi,
                                                    const short* __restrict__ Lo,
                                                    const float* __restrict__ sq,
                                                    float* __restrict__ part,
                                                    float* __restrict__ out) {
    __shared__ __align__(16) char smraw[65536];   // 2 x (16KB A | 16KB B); dump reuses 24KB

    const int tid  = threadIdx.x;
    const int lane = tid & 63;
    const int w    = tid >> 6;        // wave 0..3
    const int wy   = w >> 1;          // col half
    const int wx   = w & 1;           // row half
    const int q    = lane >> 4;       // quad 0..3
    const int pl   = lane & 15;

    const int bx   = blockIdx.x;
    const int rb   = bx & 63;
    const int cs   = bx >> 6;
    const int row0 = rb * BM;
    const int col0 = cs * CPB2;

    // staging decode: slot = w*256 + i*64 + lane -> (point, logical chunk)
    int pS[4], cS[4];
#pragma unroll
    for (int i = 0; i < 4; ++i) {
        int ch = w * 256 + i * 64 + lane;
        pS[i] = ch >> 3;
        cS[i] = (ch & 7) ^ (pS[i] & 7);
    }

    // frag LDS byte offsets: phys chunk = point*8 + (kchunk ^ (point&7))
    int colOff[4][2], rowOff[4][2];
#pragma unroll
    for (int f = 0; f < 4; ++f) {
#pragma unroll
        for (int s = 0; s < 2; ++s) {
            int pc = wy * 64 + f * 16 + pl;
            int cc = (s * 4 + q) ^ (pc & 7);
            colOff[f][s] = (pc * 64 + cc * 8) * 2;
            int pr = wx * 64 + f * 16 + pl;
            int cr = (s * 4 + q) ^ (pr & 7);
            rowOff[f][s] = (pr * 64 + cr * 8) * 2;
        }
    }

    float sqr4[4];
#pragma unroll
    for (int fj = 0; fj < 4; ++fj) sqr4[fj] = sq[row0 + wx * 64 + fj * 16 + pl];

    // packed-key top-6 per owned row (4 rows per thread)
    float bd[4][6];
#pragma unroll
    for (int fj = 0; fj < 4; ++fj)
#pragma unroll
        for (int k = 0; k < 6; ++k) bd[fj][k] = 3.0e38f;

    auto stage = [&](int b, int nt, int nk) {
        const short* plA = (nk >= 2) ? Lo : Hi;     // A sections: hi, lo
        const short* plB = Hi;                      // B sections: hi, hi
        const int half = (nk & 1) * 64;
        const int tcn  = col0 + nt * BN;
        char* baseA = smraw + b * 32768;
        char* baseB = baseA + 16384;
#pragma unroll
        for (int i = 0; i < 4; ++i) {
            const short* gA = plA + (size_t)(row0 + pS[i]) * DIM + half + cS[i] * 8;
            async16(gA, baseA + (w * 256 + i * 64) * 16);
            const short* gB = plB + (size_t)(tcn + pS[i]) * DIM + half + cS[i] * 8;
            async16(gB, baseB + (w * 256 + i * 64) * 16);
        }
    };

    stage(0, 0, 0);
    int sidx = 0;

    const f32x4 z4 = {0.f, 0.f, 0.f, 0.f};

    for (int tile = 0; tile < NT2; ++tile) {
        const int tc0 = col0 + tile * BN;

        f32x4 acc[4][4];
#pragma unroll
        for (int fi = 0; fi < 4; ++fi)
#pragma unroll
            for (int fj = 0; fj < 4; ++fj) acc[fi][fj] = 0.0f;

        for (int kk = 0; kk < KITERS; ++kk) {
            const int b = sidx & 1;
            __syncthreads();
            int nk = kk + 1, nt = tile;
            if (nk == KITERS) { nk = 0; nt = tile + 1; }
            if (nt < NT2) stage(b ^ 1, nt, nk);

            // interleaved zero-fill quota: 4 f32x4/thread/step (regular stores:
            // L2 ack drains cheaply at the next barrier; writeback is async).
            // 32 steps x 1024 f32x4 = 32768 = the full 128x1024 region.
            {
                int base = sidx * 1024 + tid;
#pragma unroll
                for (int it = 0; it < 4; ++it) {
                    int flat = base + it * 256;
                    int r  = flat >> 8;           // 0..127
                    int c4 = (flat & 255) * 4;    // 0..1020
                    *(f32x4*)&out[(size_t)(row0 + r) * NPTS + col0 + c4] = z4;
                }
            }

            char* baseA = smraw + b * 32768;
            char* baseB = baseA + 16384;
#pragma unroll
            for (int s = 0; s < 2; ++s) {
                bf16x8 cf[4], rf[4];
#pragma unroll
                for (int fi = 0; fi < 4; ++fi)
                    cf[fi] = *(const bf16x8*)(baseB + colOff[fi][s]);
#pragma unroll
                for (int fj = 0; fj < 4; ++fj)
                    rf[fj] = *(const bf16x8*)(baseA + rowOff[fj][s]);
#pragma unroll
                for (int fi = 0; fi < 4; ++fi)
#pragma unroll
                    for (int fj = 0; fj < 4; ++fj)
                        acc[fi][fj] = __builtin_amdgcn_mfma_f32_16x16x32_bf16(
                            cf[fi], rf[fj], acc[fi][fj], 0, 0, 0);
            }
            ++sidx;
        }

        // in-register epilogue: rows r = wx*64+fj*16+pl, cols c = wy*64+fi*16+q*4+reg
        const bool diag = (tc0 == row0);
        float4 sqc4[4];
#pragma unroll
        for (int fi = 0; fi < 4; ++fi)
            sqc4[fi] = *(const float4*)&sq[tc0 + wy * 64 + fi * 16 + q * 4];

#pragma unroll
        for (int fj = 0; fj < 4; ++fj) {
            const float sr = sqr4[fj];
            const int   r  = wx * 64 + fj * 16 + pl;
#pragma unroll
            for (int fi = 0; fi < 4; ++fi) {
                const float* sc = (const float*)&sqc4[fi];
#pragma unroll
                for (int reg = 0; reg < 4; ++reg) {
                    const int c = wy * 64 + fi * 16 + q * 4 + reg;
                    float d2 = fmaf(-2.0f, acc[fi][fj][reg], sr + sc[reg]);
                    d2 = fmaxf(d2, 1e-30f);
                    if (diag && r == c) d2 = 1e-30f;    // self-distance
                    uint32_t kb = (__float_as_uint(d2) & 0xFFFFFC00u)
                                  | (uint32_t)(tile * BN + c);   // 10-bit local col
                    ins6(__uint_as_float(kb), bd[fj]);
                }
            }
        }
    }

    // block merge: 8 lists per row (wy x q) -> 6 packed keys per row per split
    __syncthreads();                       // all frag reads done; reuse smraw
    float* dump = (float*)smraw;           // 128 rows * 8 copies * 6 = 24 KB
#pragma unroll
    for (int fj = 0; fj < 4; ++fj) {
        const int r    = wx * 64 + fj * 16 + pl;
        const int copy = wy * 4 + q;
        float* d = &dump[(size_t)(r * 8 + copy) * 6];
#pragma unroll
        for (int k = 0; k < 6; ++k) d[k] = bd[fj][k];
    }
    __syncthreads();
    if (tid < 128) {
        float md[6];
#pragma unroll
        for (int k = 0; k < 6; ++k) md[k] = 3.0e38f;
        const float* src = &dump[(size_t)tid * 48];
#pragma unroll
        for (int g = 0; g < 48; ++g) ins6(src[g], md);
        float* dst = part + (size_t)(row0 + tid) * 48 + cs * 6;
#pragma unroll
        for (int k = 0; k < 6; ++k) dst[k] = md[k];
    }
}

// K2: merge 8 packed-key lists per row (direct global reads, no LDS),
// compute weights, scatter 6 values.
__global__ __launch_bounds__(256) void final3(const float* __restrict__ part,
                                              float* __restrict__ out) {
    const int r = blockIdx.x * 256 + threadIdx.x;
    const float4* p4 = (const float4*)(part + (size_t)r * 48);
    float4 buf[12];
#pragma unroll
    for (int i = 0; i < 12; ++i) buf[i] = p4[i];
    const float* keys = (const float*)buf;

    float md[6]; int mi[6];
#pragma unroll
    for (int k = 0; k < 6; ++k) { md[k] = 3.0e38f; mi[k] = 0; }
#pragma unroll
    for (int s = 0; s < 8; ++s)
#pragma unroll
        for (int k = 0; k < 6; ++k) {
            uint32_t kb = __float_as_uint(keys[s * 6 + k]);
            float d2 = __uint_as_float(kb & 0xFFFFFC00u);
            int  col = s * CPB2 + (int)(kb & 1023u);
            insert6(d2, col, md, mi);
        }
    const float T = sqrtf(md[5]);
    float wv[6], norm = 0.f;
#pragma unroll
    for (int k = 0; k < 6; ++k) { wv[k] = T - sqrtf(md[k]) + 1e-10f; norm += wv[k]; }
    const float inv = 1.0f / fmaxf(norm, 1e-12f);
    const size_t base = (size_t)r * NPTS;
#pragma unroll
    for (int k = 0; k < 6; ++k) out[base + mi[k]] = wv[k] * inv;
}

// ------------------- fallback fp32 path (round 1, passing) -------------------
#define RB      32
#define CT      64
#define SPLITS  8
#define CPB     (NPTS / SPLITS)
#define NTILES  (CPB / CT)
#define PADS    132

__global__ __launch_bounds__(256) void knn_partial(const float* __restrict__ F,
                                                   float* __restrict__ out) {
    __shared__ float rowF[RB * PADS];
    __shared__ float colF[CT * PADS];
    __shared__ float sqr[RB];
    __shared__ float sqc[CT];

    const int tid  = threadIdx.x;
    const int bx   = blockIdx.x;
    const int rb   = bx & ((NPTS / RB) - 1);
    const int cs   = bx >> 8;
    const int row0 = rb * RB;
    const int col0 = cs * CPB;

#pragma unroll
    for (int m = 0; m < 4; ++m) {
        int flat = m * 256 + tid;
        int r = flat >> 5, kq = flat & 31;
        float4 v = *(const float4*)&F[(size_t)(row0 + r) * DIM + kq * 4];
        *(float4*)&rowF[r * PADS + kq * 4] = v;
    }
    __syncthreads();
    if (tid < RB) {
        float s = 0.f;
#pragma unroll
        for (int kq = 0; kq < 32; ++kq) {
            float4 v = *(const float4*)&rowF[tid * PADS + kq * 4];
            s += v.x * v.x + v.y * v.y + v.z * v.z + v.w * v.w;
        }
        sqr[tid] = s;
    }

    const int rl = tid >> 4;
    const int cl = tid & 15;

    float bd[2][6];
    int   bi[2][6];
#pragma unroll
    for (int i = 0; i < 2; ++i)
#pragma unroll
        for (int k = 0; k < 6; ++k) { bd[i][k] = 3.0e38f; bi[i][k] = 0; }

    for (int t = 0; t < NTILES; ++t) {
        const int cbase = col0 + t * CT;
        __syncthreads();
#pragma unroll
        for (int m = 0; m < 8; ++m) {
            int flat = m * 256 + tid;
            int c = flat >> 5, kq = flat & 31;
            float4 v = *(const float4*)&F[(size_t)(cbase + c) * DIM + kq * 4];
            *(float4*)&colF[c * PADS + kq * 4] = v;
        }
        __syncthreads();
        if (tid < CT) {
            float s = 0.f;
#pragma unroll
            for (int kq = 0; kq < 32; ++kq) {
                float4 v = *(const float4*)&colF[tid * PADS + kq * 4];
                s += v.x * v.x + v.y * v.y + v.z * v.z + v.w * v.w;
            }
            sqc[tid] = s;
        }
        __syncthreads();

        float acc[2][4];
#pragma unroll
        for (int i = 0; i < 2; ++i)
#pragma unroll
            for (int j = 0; j < 4; ++j) acc[i][j] = 0.f;

#pragma unroll 4
        for (int kq = 0; kq < 32; ++kq) {
            float4 a[2], b[4];
#pragma unroll
            for (int i = 0; i < 2; ++i)
                a[i] = *(const float4*)&rowF[(rl + 16 * i) * PADS + kq * 4];
#pragma unroll
            for (int j = 0; j < 4; ++j)
                b[j] = *(const float4*)&colF[(cl + 16 * j) * PADS + kq * 4];
#pragma unroll
            for (int i = 0; i < 2; ++i)
#pragma unroll
                for (int j = 0; j < 4; ++j) {
                    acc[i][j] = fmaf(a[i].x, b[j].x, acc[i][j]);
                    acc[i][j] = fmaf(a[i].y, b[j].y, acc[i][j]);
                    acc[i][j] = fmaf(a[i].z, b[j].z, acc[i][j]);
                    acc[i][j] = fmaf(a[i].w, b[j].w, acc[i][j]);
                }
        }

#pragma unroll
        for (int i = 0; i < 2; ++i) {
            const int r = rl + 16 * i;
            const int gr = row0 + r;
#pragma unroll
            for (int j = 0; j < 4; ++j) {
                const int c = cl + 16 * j;
                const int gc = cbase + c;
                float d2 = sqr[r] + sqc[c] - 2.0f * acc[i][j];
                d2 = (gr == gc) ? 1e-30f : fmaxf(d2, 1e-30f);
                insert6(d2, gc, bd[i], bi[i]);
            }
        }
    }

    __syncthreads();
    float* cd = colF;
    float* ci = rowF;
#pragma unroll
    for (int i = 0; i < 2; ++i) {
        const int r = rl + 16 * i;
#pragma unroll
        for (int k = 0; k < 6; ++k) {
            cd[(r * 16 + cl) * 6 + k] = bd[i][k];
            ci[(r * 16 + cl) * 6 + k] = __int_as_float(bi[i][k]);
        }
    }
    __syncthreads();
    if (tid < RB) {
        float md[6]; int mi[6];
#pragma unroll
        for (int k = 0; k < 6; ++k) { md[k] = 3.0e38f; mi[k] = 0; }
        for (int g = 0; g < 16; ++g) {
#pragma unroll
            for (int k = 0; k < 6; ++k)
                insert6(cd[(tid * 16 + g) * 6 + k],
                        __float_as_int(ci[(tid * 16 + g) * 6 + k]), md, mi);
        }
        float* dst = &out[(size_t)(row0 + tid) * NPTS + cs * 12];
#pragma unroll
        for (int k = 0; k < 6; ++k) {
            dst[k] = md[k];
            dst[6 + k] = __int_as_float(mi[k]);
        }
    }
}

__global__ __launch_bounds__(256) void knn_finalize(float* __restrict__ out) {
    __shared__ float pbuf[SPLITS * 12];
    __shared__ float w_s[6];
    __shared__ int   wi_s[6];

    const int    tid  = threadIdx.x;
    const size_t base = (size_t)blockIdx.x * NPTS;

    if (tid < SPLITS * 12) pbuf[tid] = out[base + tid];
    __syncthreads();

    if (tid == 0) {
        float md[6]; int mi[6];
#pragma unroll
        for (int k = 0; k < 6; ++k) { md[k] = 3.0e38f; mi[k] = 0; }
        for (int s = 0; s < SPLITS; ++s)
#pragma unroll
            for (int k = 0; k < 6; ++k)
                insert6(pbuf[s * 12 + k], __float_as_int(pbuf[s * 12 + 6 + k]), md, mi);
        const float T = sqrtf(md[5]);
        float w[6]; float norm = 0.f;
#pragma unroll
        for (int k = 0; k < 6; ++k) { w[k] = T - sqrtf(md[k]) + 1e-10f; norm += w[k]; }
        const float inv = 1.0f / fmaxf(norm, 1e-12f);
#pragma unroll
        for (int k = 0; k < 6; ++k) { w_s[k] = w[k] * inv; wi_s[k] = mi[k]; }
    }
    __syncthreads();

#pragma unroll
    for (int m = 0; m < 8; ++m)
        *(float4*)&out[base + (size_t)(m * 256 + tid) * 4] = make_float4(0.f, 0.f, 0.f, 0.f);
    __syncthreads();

    if (tid < 6) out[base + wi_s[tid]] = w_s[tid];
}

extern "C" void kernel_launch(void* const* d_in, const int* in_sizes, int n_in,
                              void* d_out, int out_size, void* d_ws, size_t ws_size,
                              hipStream_t stream) {
    const float* F   = (const float*)d_in[0];
    float*       out = (float*)d_out;
    if (ws_size >= WS_NEED) {
        short* Hi  = (short*)((char*)d_ws + WS_HI);
        short* Lo  = (short*)((char*)d_ws + WS_LO);
        float* sqp = (float*)((char*)d_ws + WS_SQ);
        float* prt = (float*)((char*)d_ws + WS_PART);
        prep2<<<dim3(NPTS * DIM / 256), dim3(256), 0, stream>>>(F, Hi, Lo, sqp);
        knn_mfma3<<<dim3(64 * NSPLIT), dim3(256), 0, stream>>>(Hi, Lo, sqp, prt, out);
        final3<<<dim3(NPTS / 256), dim3(256), 0, stream>>>(prt, out);
    } else {
        knn_partial<<<dim3((NPTS / RB) * SPLITS), dim3(256), 0, stream>>>(F, out);
        knn_finalize<<<dim3(NPTS), dim3(256), 0, stream>>>(out);
    }
}